// Round 4
// baseline (13.263 us; speedup 1.0000x reference)
//
#include <hip/hip_runtime.h>
#include <math.h>

// Shapelet distance + softmin pooling.
// x: (8, 8, 2048) f32, w: (32, 8, 32) f32
// out: [pred (8*256), d_min (8*256)] f32
//
// d2(b,t,n,m) = sum_l (x[b,m,t+l] - w[n,m,l])^2
//             = x2(t) + w2 - 2*dot(t)              (>= 0, clip is no-op)
// pred(b,n,m) = exp(-d2min + log(sum_t exp(-10*d2))/10)
// dmin(b,n,m) = sqrt(d2min)

#define T_VALID 2017
#define K10 14.426950408889634f   // 10 / ln(2):  exp(10*z) == exp2(K10*z)

// (1024, 4): 4 waves/EU minimum -> VGPR cap 128, stops the backend's
// spill-for-occupancy heuristic (round 3: VGPR_Count=48 => scratch spills;
// grid is 1 block/CU so >4 waves/SIMD is unreachable anyway).
__global__ __launch_bounds__(1024, 4) void shapelet_kernel(
    const float* __restrict__ x,
    const float* __restrict__ w,
    float* __restrict__ out)
{
    const int bid = blockIdx.x;
    const int b = bid >> 5;       // 0..7
    const int n = bid & 31;       // 0..31
    const int tid = threadIdx.x;
    const int m = tid >> 7;       // 0..7
    const int tq = tid & 127;     // 0..127 (t-group lane within m-group)

    // --- weights for (n, m): 32 floats in registers (broadcast within m-group)
    const float4* w4 = reinterpret_cast<const float4*>(w + (((n << 3) + m) << 5));
    float wr[32];
    #pragma unroll
    for (int j = 0; j < 8; ++j) {
        float4 v = w4[j];
        wr[4 * j + 0] = v.x; wr[4 * j + 1] = v.y;
        wr[4 * j + 2] = v.z; wr[4 * j + 3] = v.w;
    }
    float w2c = 0.0f;
    #pragma unroll
    for (int l = 0; l < 32; ++l) w2c = fmaf(wr[l], wr[l], w2c);

    // x row for (b, m): 2048 floats = 512 float4
    const float4* x4 = reinterpret_cast<const float4*>(x + (((b << 3) + m) << 11));

    float mrun = INFINITY;  // running min d2
    float S = 0.0f;         // sum_t exp2(K10*(mrun - d2))

    // Each thread: 8 consecutive t per k-iter; tt = k*128 + tq; t = 8*tt .. 8*tt+7.
    // 2 k-iters * 128 lanes * 8 t = 2048 t (2017 valid, rest masked).
    #pragma unroll 1
    for (int k = 0; k < 2; ++k) {
        const int tt = (k << 7) + tq;
        // register window x[8*tt .. 8*tt+39] as 10 coalesced float4 loads
        float xs[40];
        #pragma unroll
        for (int j = 0; j < 10; ++j) {
            int idx = (tt << 1) + j;
            idx = idx > 511 ? 511 : idx;   // clamp (feeds only masked t)
            float4 v = x4[idx];
            xs[4 * j + 0] = v.x; xs[4 * j + 1] = v.y;
            xs[4 * j + 2] = v.z; xs[4 * j + 3] = v.w;
        }
        // sliding sum of squares for the 8 windows
        float ss = 0.0f;
        #pragma unroll
        for (int l = 0; l < 32; ++l) ss = fmaf(xs[l], xs[l], ss);
        float x2v[8];
        x2v[0] = ss;
        #pragma unroll
        for (int dt = 1; dt < 8; ++dt)
            x2v[dt] = fmaf(xs[dt + 31], xs[dt + 31], x2v[dt - 1]) - xs[dt - 1] * xs[dt - 1];
        // dot products (8 independent chains, 1 fma per (t,l))
        float dv[8];
        #pragma unroll
        for (int dt = 0; dt < 8; ++dt) dv[dt] = 0.0f;
        #pragma unroll
        for (int l = 0; l < 32; ++l) {
            const float wl = wr[l];
            #pragma unroll
            for (int dt = 0; dt < 8; ++dt)
                dv[dt] = fmaf(xs[l + dt], wl, dv[dt]);
        }
        const int t0 = tt << 3;
        float d2[8];
        #pragma unroll
        for (int dt = 0; dt < 8; ++dt)
            d2[dt] = (t0 + dt < T_VALID) ? fmaf(-2.0f, dv[dt], x2v[dt] + w2c) : INFINITY;
        // online softmin update (one rescale per 8-t tile)
        float tmin = fminf(fminf(fminf(d2[0], d2[1]), fminf(d2[2], d2[3])),
                           fminf(fminf(d2[4], d2[5]), fminf(d2[6], d2[7])));
        float nm = fminf(mrun, tmin);
        float s_tile = 0.0f;
        #pragma unroll
        for (int dt = 0; dt < 8; ++dt)
            s_tile += exp2f(K10 * (nm - d2[dt]));
        S = S * exp2f(K10 * (nm - mrun)) + s_tile;
        mrun = nm;
    }

    // --- wave-level reduce (64 lanes, all same m): LSE merge + min
    #pragma unroll
    for (int off = 32; off > 0; off >>= 1) {
        float om = __shfl_xor(mrun, off);
        float oS = __shfl_xor(S, off);
        float nm = fminf(mrun, om);
        S = S * exp2f(K10 * (nm - mrun)) + oS * exp2f(K10 * (nm - om));
        mrun = nm;
    }

    // --- combine the two waves of each m-group via LDS
    __shared__ float pm[16], pS[16];
    const int wid = tid >> 6;          // 0..15 (wave -> m = wid>>1)
    if ((tid & 63) == 0) { pm[wid] = mrun; pS[wid] = S; }
    __syncthreads();
    if (tid < 8) {
        const float m0 = pm[2 * tid], S0 = pS[2 * tid];
        const float m1 = pm[2 * tid + 1], S1 = pS[2 * tid + 1];
        const float nm = fminf(m0, m1);
        const float Sx = S0 * exp2f(K10 * (nm - m0)) + S1 * exp2f(K10 * (nm - m1));
        const int o = (b << 8) + (n << 3) + tid;
        // pooled = -nm + log(Sx)/10 ; pred = exp(pooled)
        out[o] = expf(-nm + 0.1f * logf(Sx));
        out[2048 + o] = sqrtf(nm);
    }
}

extern "C" void kernel_launch(void* const* d_in, const int* in_sizes, int n_in,
                              void* d_out, int out_size, void* d_ws, size_t ws_size,
                              hipStream_t stream) {
    const float* x = (const float*)d_in[0];   // (8,8,2048)
    const float* w = (const float*)d_in[1];   // (32,8,32)
    float* out = (float*)d_out;               // 4096 floats
    hipLaunchKernelGGL(shapelet_kernel, dim3(256), dim3(1024), 0, stream, x, w, out);
}

// Round 5
// 12.918 us; speedup vs baseline: 1.0267x; 1.0267x over previous
//
#include <hip/hip_runtime.h>
#include <math.h>

// Shapelet distance + softmin pooling.
// x: (8, 8, 2048) f32, w: (32, 8, 32) f32
// out: [pred (8*256), d_min (8*256)] f32
//
// d2(b,t,n,m) = sum_l (x[b,m,t+l] - w[n,m,l])^2
//             = x2(t) + w2 - 2*dot(t)              (>= 0, clip is no-op)
// pred(b,n,m) = exp(-d2min + log(sum_t exp(-10*d2))/10)
// dmin(b,n,m) = sqrt(d2min)

#define T_VALID 2017
#define K10 14.426950408889634f   // 10 / ln(2):  exp(10*z) == exp2(K10*z)

// waves_per_eu(4,4): pin occupancy target to exactly 4 waves/EU (grid is
// 1 block/CU -> more is unreachable). launch_bounds(1024,4) alone only sets
// the MINIMUM waves/EU, so the backend kept its 8+-wave 48-VGPR spill
// allocation (rounds 3-4 identical timing). This unlocks 128 VGPRs.
__global__ __launch_bounds__(1024)
__attribute__((amdgpu_waves_per_eu(4, 4)))
void shapelet_kernel(
    const float* __restrict__ x,
    const float* __restrict__ w,
    float* __restrict__ out)
{
    const int bid = blockIdx.x;
    const int b = bid >> 5;       // 0..7
    const int n = bid & 31;       // 0..31
    const int tid = threadIdx.x;
    const int m = tid >> 7;       // 0..7
    const int tq = tid & 127;     // 0..127 (t-group lane within m-group)

    // --- weights for (n, m): 32 floats in registers (broadcast within m-group)
    const float4* w4 = reinterpret_cast<const float4*>(w + (((n << 3) + m) << 5));
    float wr[32];
    #pragma unroll
    for (int j = 0; j < 8; ++j) {
        float4 v = w4[j];
        wr[4 * j + 0] = v.x; wr[4 * j + 1] = v.y;
        wr[4 * j + 2] = v.z; wr[4 * j + 3] = v.w;
    }
    float w2c = 0.0f;
    #pragma unroll
    for (int l = 0; l < 32; ++l) w2c = fmaf(wr[l], wr[l], w2c);

    // x row for (b, m): 2048 floats = 512 float4
    const float4* x4 = reinterpret_cast<const float4*>(x + (((b << 3) + m) << 11));

    float mrun = INFINITY;  // running min d2
    float S = 0.0f;         // sum_t exp2(K10*(mrun - d2))

    // Each thread: 8 consecutive t per k-iter; tt = k*128 + tq; t = 8*tt .. 8*tt+7.
    // 2 k-iters * 128 lanes * 8 t = 2048 t (2017 valid, rest masked).
    #pragma unroll 1
    for (int k = 0; k < 2; ++k) {
        const int tt = (k << 7) + tq;
        // register window x[8*tt .. 8*tt+39] as 10 coalesced float4 loads
        float xs[40];
        #pragma unroll
        for (int j = 0; j < 10; ++j) {
            int idx = (tt << 1) + j;
            idx = idx > 511 ? 511 : idx;   // clamp (feeds only masked t)
            float4 v = x4[idx];
            xs[4 * j + 0] = v.x; xs[4 * j + 1] = v.y;
            xs[4 * j + 2] = v.z; xs[4 * j + 3] = v.w;
        }
        // sliding sum of squares for the 8 windows
        float ss = 0.0f;
        #pragma unroll
        for (int l = 0; l < 32; ++l) ss = fmaf(xs[l], xs[l], ss);
        float x2v[8];
        x2v[0] = ss;
        #pragma unroll
        for (int dt = 1; dt < 8; ++dt)
            x2v[dt] = fmaf(xs[dt + 31], xs[dt + 31], x2v[dt - 1]) - xs[dt - 1] * xs[dt - 1];
        // dot products (8 independent chains, 1 fma per (t,l))
        float dv[8];
        #pragma unroll
        for (int dt = 0; dt < 8; ++dt) dv[dt] = 0.0f;
        #pragma unroll
        for (int l = 0; l < 32; ++l) {
            const float wl = wr[l];
            #pragma unroll
            for (int dt = 0; dt < 8; ++dt)
                dv[dt] = fmaf(xs[l + dt], wl, dv[dt]);
        }
        const int t0 = tt << 3;
        float d2[8];
        #pragma unroll
        for (int dt = 0; dt < 8; ++dt)
            d2[dt] = (t0 + dt < T_VALID) ? fmaf(-2.0f, dv[dt], x2v[dt] + w2c) : INFINITY;
        // online softmin update (one rescale per 8-t tile)
        float tmin = fminf(fminf(fminf(d2[0], d2[1]), fminf(d2[2], d2[3])),
                           fminf(fminf(d2[4], d2[5]), fminf(d2[6], d2[7])));
        float nm = fminf(mrun, tmin);
        float s_tile = 0.0f;
        #pragma unroll
        for (int dt = 0; dt < 8; ++dt)
            s_tile += exp2f(K10 * (nm - d2[dt]));
        S = S * exp2f(K10 * (nm - mrun)) + s_tile;
        mrun = nm;
    }

    // --- wave-level reduce (64 lanes, all same m): LSE merge + min
    #pragma unroll
    for (int off = 32; off > 0; off >>= 1) {
        float om = __shfl_xor(mrun, off);
        float oS = __shfl_xor(S, off);
        float nm = fminf(mrun, om);
        S = S * exp2f(K10 * (nm - mrun)) + oS * exp2f(K10 * (nm - om));
        mrun = nm;
    }

    // --- combine the two waves of each m-group via LDS
    __shared__ float pm[16], pS[16];
    const int wid = tid >> 6;          // 0..15 (wave -> m = wid>>1)
    if ((tid & 63) == 0) { pm[wid] = mrun; pS[wid] = S; }
    __syncthreads();
    if (tid < 8) {
        const float m0 = pm[2 * tid], S0 = pS[2 * tid];
        const float m1 = pm[2 * tid + 1], S1 = pS[2 * tid + 1];
        const float nm = fminf(m0, m1);
        const float Sx = S0 * exp2f(K10 * (nm - m0)) + S1 * exp2f(K10 * (nm - m1));
        const int o = (b << 8) + (n << 3) + tid;
        // pooled = -nm + log(Sx)/10 ; pred = exp(pooled)
        out[o] = expf(-nm + 0.1f * logf(Sx));
        out[2048 + o] = sqrtf(nm);
    }
}

extern "C" void kernel_launch(void* const* d_in, const int* in_sizes, int n_in,
                              void* d_out, int out_size, void* d_ws, size_t ws_size,
                              hipStream_t stream) {
    const float* x = (const float*)d_in[0];   // (8,8,2048)
    const float* w = (const float*)d_in[1];   // (32,8,32)
    float* out = (float*)d_out;               // 4096 floats
    hipLaunchKernelGGL(shapelet_kernel, dim3(256), dim3(1024), 0, stream, x, w, out);
}